// Round 5
// baseline (80.583 us; speedup 1.0000x reference)
//
#include <hip/hip_runtime.h>

#define DIM    64      // CELL_DIM
#define NCELLS 512
#define ROWS_PER_BLOCK 32
#define NROWS  8192
#define NBLOCKS (NROWS / ROWS_PER_BLOCK)   // 256 = one block per CU

// R5: fix LDS-read-pipe bound. R4 (2 rows/wave) demanded 128 B/cyc of LDS read
// per CU vs the ~85 B/cyc ds_read_b128 ceiling -> K-loop was LDS-limited
// (~10.3 us) above the 6.8 us VALU floor. This version: 4 rows/wave -> each
// ds_read_b128 pair feeds 128 VALU-cycles (demand 64 B/cyc < 85) -> VALU-bound.
// Geometry: 512 threads = 8 waves x 4 rows = 32 rows/block, 256 blocks,
// 1 block/CU (128 KB LDS), 2 waves/SIMD. Single staging pass, ONE barrier.
// Accumulators are named float4s (R2 lesson: no runtime-selected refs/indices).
__global__ __launch_bounds__(512, 2)
void placecells_kernel(const float* __restrict__ x,
                       const float* __restrict__ pc,
                       float* __restrict__ out)
{
    extern __shared__ float pcT[];   // [64 k][512 cells] = 128 KB, quad-swizzled

    const int tid = (int)threadIdx.x;
    const int l   = tid & 63;
    const int w   = __builtin_amdgcn_readfirstlane(tid >> 6);
    const int rowBase = (int)blockIdx.x * ROWS_PER_BLOCK + w * 4;

    // ---- stage ALL of pc once: global [cell][k] -> LDS pcT[k][cell] ----
    // 512 cells x 16 k-quads = 8192 float4s over 512 threads = 16 iters.
    // Global: 16 consecutive lanes cover one cell's 256 B -> 1 KB/wave, coalesced.
    // LDS write banks: (pq*4 + cl&3) mod 32 -> 32 banks x 2 lanes = free 2-way.
    #pragma unroll
    for (int it = 0; it < 16; ++it) {
        int idx = it * 512 + tid;         // 0..8191
        int cl  = idx >> 4;               // cell, 0..511
        int kq  = idx & 15;               // k-quad, 0..15
        float4 v = *(const float4*)(pc + cl * DIM + kq * 4);
        int pq = (cl >> 2) ^ kq;          // swizzle 16B quads within each k-row
        float* p = &pcT[(kq * 4) * NCELLS + pq * 4 + (cl & 3)];
        p[0 * NCELLS] = v.x;
        p[1 * NCELLS] = v.y;
        p[2 * NCELLS] = v.z;
        p[3 * NCELLS] = v.w;
    }
    __syncthreads();   // the ONLY barrier in the kernel

    // a{row}{chunk}: 4 rows x 2 chunks x 4 cells -> 32 accumulator VGPRs
    float4 a0A{0,0,0,0}, a0B{0,0,0,0};
    float4 a1A{0,0,0,0}, a1B{0,0,0,0};
    float4 a2A{0,0,0,0}, a2B{0,0,0,0};
    float4 a3A{0,0,0,0}, a3B{0,0,0,0};

    // ---- K loop: per j, 2 conflict-free ds_read_b128 feed 64 VALU insts ----
    #pragma unroll 4
    for (int k4 = 0; k4 < 16; ++k4) {
        // wave-uniform x addresses (scalarizable; proven off-critical-path in R1)
        float4 xv0 = *(const float4*)(x + (rowBase + 0) * DIM + k4 * 4);
        float4 xv1 = *(const float4*)(x + (rowBase + 1) * DIM + k4 * 4);
        float4 xv2 = *(const float4*)(x + (rowBase + 2) * DIM + k4 * 4);
        float4 xv3 = *(const float4*)(x + (rowBase + 3) * DIM + k4 * 4);
        const int pqA = (l ^ k4) * 4;     // undo swizzle: logical quad = l
        #pragma unroll
        for (int j = 0; j < 4; ++j) {
            const float* rowp = &pcT[(k4 * 4 + j) * NCELLS];
            float4 pvA = *(const float4*)(rowp + pqA);        // cells 4l..4l+3
            float4 pvB = *(const float4*)(rowp + pqA + 256);  // cells 256+4l..+3
            float x0 = (j == 0) ? xv0.x : (j == 1) ? xv0.y : (j == 2) ? xv0.z : xv0.w;
            float x1 = (j == 0) ? xv1.x : (j == 1) ? xv1.y : (j == 2) ? xv1.z : xv1.w;
            float x2 = (j == 0) ? xv2.x : (j == 1) ? xv2.y : (j == 2) ? xv2.z : xv2.w;
            float x3 = (j == 0) ? xv3.x : (j == 1) ? xv3.y : (j == 2) ? xv3.z : xv3.w;
            a0A.x += fabsf(x0 - pvA.x); a0A.y += fabsf(x0 - pvA.y);
            a0A.z += fabsf(x0 - pvA.z); a0A.w += fabsf(x0 - pvA.w);
            a0B.x += fabsf(x0 - pvB.x); a0B.y += fabsf(x0 - pvB.y);
            a0B.z += fabsf(x0 - pvB.z); a0B.w += fabsf(x0 - pvB.w);
            a1A.x += fabsf(x1 - pvA.x); a1A.y += fabsf(x1 - pvA.y);
            a1A.z += fabsf(x1 - pvA.z); a1A.w += fabsf(x1 - pvA.w);
            a1B.x += fabsf(x1 - pvB.x); a1B.y += fabsf(x1 - pvB.y);
            a1B.z += fabsf(x1 - pvB.z); a1B.w += fabsf(x1 - pvB.w);
            a2A.x += fabsf(x2 - pvA.x); a2A.y += fabsf(x2 - pvA.y);
            a2A.z += fabsf(x2 - pvA.z); a2A.w += fabsf(x2 - pvA.w);
            a2B.x += fabsf(x2 - pvB.x); a2B.y += fabsf(x2 - pvB.y);
            a2B.z += fabsf(x2 - pvB.z); a2B.w += fabsf(x2 - pvB.w);
            a3A.x += fabsf(x3 - pvA.x); a3A.y += fabsf(x3 - pvA.y);
            a3A.z += fabsf(x3 - pvA.z); a3A.w += fabsf(x3 - pvA.w);
            a3B.x += fabsf(x3 - pvB.x); a3B.y += fabsf(x3 - pvB.y);
            a3B.z += fabsf(x3 - pvB.z); a3B.w += fabsf(x3 - pvB.w);
        }
    }

    // ---- softmax per row over 512 cells (one wave holds a whole row) ----
    auto finish_row = [&](float4 a, float4 b, int r) {
        // min L1 == min d^2 (d >= 0) -> exact max-subtraction
        float mn = fminf(fminf(fminf(a.x, a.y), fminf(a.z, a.w)),
                         fminf(fminf(b.x, b.y), fminf(b.z, b.w)));
        #pragma unroll
        for (int off = 32; off > 0; off >>= 1)
            mn = fminf(mn, __shfl_xor(mn, off, 64));
        float m2 = mn * mn;

        float e0 = __expf(0.5f * (m2 - a.x * a.x));
        float e1 = __expf(0.5f * (m2 - a.y * a.y));
        float e2 = __expf(0.5f * (m2 - a.z * a.z));
        float e3 = __expf(0.5f * (m2 - a.w * a.w));
        float e4 = __expf(0.5f * (m2 - b.x * b.x));
        float e5 = __expf(0.5f * (m2 - b.y * b.y));
        float e6 = __expf(0.5f * (m2 - b.z * b.z));
        float e7 = __expf(0.5f * (m2 - b.w * b.w));
        float s = ((e0 + e1) + (e2 + e3)) + ((e4 + e5) + (e6 + e7));
        #pragma unroll
        for (int off = 32; off > 0; off >>= 1)
            s += __shfl_xor(s, off, 64);
        float inv = 1.0f / s;

        float* orow = out + (size_t)(rowBase + r) * NCELLS;
        *(float4*)(orow + 4 * l)       = make_float4(e0 * inv, e1 * inv, e2 * inv, e3 * inv);
        *(float4*)(orow + 256 + 4 * l) = make_float4(e4 * inv, e5 * inv, e6 * inv, e7 * inv);
    };
    finish_row(a0A, a0B, 0);
    finish_row(a1A, a1B, 1);
    finish_row(a2A, a2B, 2);
    finish_row(a3A, a3B, 3);
}

extern "C" void kernel_launch(void* const* d_in, const int* in_sizes, int n_in,
                              void* d_out, int out_size, void* d_ws, size_t ws_size,
                              hipStream_t stream)
{
    const float* x  = (const float*)d_in[0];   // (8192, 64) fp32
    const float* pc = (const float*)d_in[1];   // (512, 64) fp32
    float* out = (float*)d_out;                // (8192, 512) fp32
    placecells_kernel<<<dim3(NBLOCKS), dim3(512), DIM * NCELLS * sizeof(float), stream>>>(x, pc, out);
}